// Round 15
// baseline (481.927 us; speedup 1.0000x reference)
//
#include <hip/hip_runtime.h>
#include <hip/hip_fp16.h>

// clusteringEMA: B=65536, D=512, K=1024, C=100
// R15: r12 streaming argmin (Xh f16, BK=64, conflict-free maps) upgraded to a
// TRIPLE-BUFFERED 2-deep pipeline with counted s_waitcnt vmcnt(8) and raw
// s_barrier (T4: never drain vmcnt to 0 in the main loop). r14's A-resident
// 1-block/CU drain-chain regression reverted.
// ws layout = r12 audited: WTHI 353344+262144->615488; WT32 +524288->1139776;
// XH 1139776+16777216->17916992; ESUM +524288->18441280 (*4 = 73.8MB)

#define NB 65536
#define ND 512
#define NK 1024
#define NC 100
#define TAU 0.25f
#define FLAG_CAP 16384
#define FROWS 8
#define GROWS 128

typedef unsigned int u32;
typedef unsigned short u16;
typedef unsigned long long u64;
typedef __attribute__((ext_vector_type(8))) _Float16 half8v;
typedef __attribute__((ext_vector_type(4))) float f32x4;

// ---------------- ws layout (4-byte units) ----------------
#define OFF_COUNTS   0          // int [1024]
#define OFF_CURSOR   1024       // int [1024]
#define OFF_BHIST    2048       // float [102400]
#define OFF_FLAGCNT  104448     // int [64]
#define OFF_WSQ      104512     // float [1024]
#define OFF_ZERO_END 105536
#define OFF_FLAGLIST 105536     // int [16384]
#define OFF_FKEYS    121920     // u64 [16384]
#define OFF_CSNORM   154688     // float [1024]
#define OFF_OFFSETS  155712     // int [1024]
#define OFF_ARGMIN   156736     // int [65536]
#define OFF_ORDER    222272     // int [65536]
#define OFF_KORDER   287808     // int [65536]
#define OFF_WTHI     353344     // u16 [524288] = 262144 float slots
#define OFF_WT32     615488     // float [524288]
#define OFF_XH       1139776    // u16 [33554432] = 16777216 float slots
#define OFF_ESUM     17916992   // float [524288]

__device__ inline f32x4 mfma16f(half8v a, half8v b, f32x4 c) {
  return __builtin_amdgcn_mfma_f32_16x16x32_f16(a, b, c, 0, 0, 0);
}

__device__ __forceinline__ void gl_lds16(const u16* g, u16* l) {
  __builtin_amdgcn_global_load_lds(
      (const __attribute__((address_space(1))) u32*)g,
      (__attribute__((address_space(3))) u32*)l, 16, 0, 0);
}

__device__ inline u32 f32_sortable(float f) {
  u32 b = __float_as_uint(f);
  return (b & 0x80000000u) ? ~b : (b | 0x80000000u);
}

__device__ inline half8v cvt8_f16(const float4& a, const float4& b) {
  half8v h;
  h[0] = (_Float16)a.x; h[1] = (_Float16)a.y;
  h[2] = (_Float16)a.z; h[3] = (_Float16)a.w;
  h[4] = (_Float16)b.x; h[5] = (_Float16)b.y;
  h[6] = (_Float16)b.z; h[7] = (_Float16)b.w;
  return h;
}

// ------ kernel 0: X -> Xh (f16 RNE), one pass ------
__global__ __launch_bounds__(256) void prep_x(const float* __restrict__ X,
                                              u16* __restrict__ Xh) {
  size_t i = ((size_t)blockIdx.x * 256 + threadIdx.x) * 8;
  float4 a = *(const float4*)(X + i);
  float4 b = *(const float4*)(X + i + 4);
  *(half8v*)(Xh + i) = cvt8_f16(a, b);
}

// ------ kernel 1: W -> Wt (transposed; f16 RNE + f32) + wsq ------
__global__ __launch_bounds__(256) void prep_w(const float* __restrict__ W,
                                              u16* __restrict__ Wthi,
                                              float* __restrict__ Wt32,
                                              float* __restrict__ wsq) {
  __shared__ float tile[32][33];
  int db = blockIdx.x & 15;
  int kb = blockIdx.x >> 4;
  int tx = threadIdx.x & 31, ty = threadIdx.x >> 5;
  float s = 0.f;
#pragma unroll
  for (int i = 0; i < 4; ++i) {
    int d = db * 32 + ty + 8 * i;
    float wv = W[(size_t)d * NK + kb * 32 + tx];
    tile[ty + 8 * i][tx] = wv;
    s += wv * wv;
  }
  atomicAdd(&wsq[kb * 32 + tx], s);
  __syncthreads();
#pragma unroll
  for (int i = 0; i < 4; ++i) {
    int kl = ty + 8 * i;
    float f = tile[tx][kl];
    size_t o = (size_t)(kb * 32 + kl) * ND + db * 32 + tx;
    Wt32[o] = f;
    Wthi[o] = __half_as_ushort(__float2half(f));
  }
}

// --- kernel 2: argmin MFMA, triple-buffered counted-vmcnt pipeline ----------
__global__ __launch_bounds__(256, 1) void argmin_tri(
    const u16* __restrict__ Xh, const u16* __restrict__ Wthi,
    const float* __restrict__ wsq, const int* __restrict__ cls,
    int* __restrict__ argmin_i, float* __restrict__ argmin_f,
    int* __restrict__ counts, float* __restrict__ bhist,
    int* __restrict__ flagCnt, int* __restrict__ flagList) {
  __shared__ __align__(16) u16 Ah[3 * 128 * 64];   // 3 x 16KB
  __shared__ __align__(16) u16 Bh[3 * 128 * 64];   // 3 x 16KB
  __shared__ float wsq_s[NK];                      // 4KB
  __shared__ float redV[128][2];
  __shared__ float redS[128][2];
  __shared__ int redI[128][2];                     // total 105472 B

  const int t = threadIdx.x;
  const int lane = t & 63;
  const int w = t >> 6;
  const int g = lane >> 4;
  const int l15 = lane & 15;
  const int wrb = (w >> 1) * 64;
  const int wcb = (w & 1) * 64;
  const int brow = blockIdx.x * 128;

#pragma unroll
  for (int i = 0; i < 4; ++i) wsq_s[t + 256 * i] = wsq[t + 256 * i];

  // staging maps (r12, measured conflict-free): lane -> (row sub, phys chunk
  // c8p), source chunk = c8p ^ sub (3-bit involution)
  const int sub = lane >> 3;
  const int c8p = lane & 7;
  const size_t asrc = (size_t)(brow + w * 32 + sub) * ND + (size_t)((c8p ^ sub) * 8);
  const size_t bsrc = (size_t)(w * 32 + sub) * ND + (size_t)((c8p ^ sub) * 8);

  int aofs[2], bofs[2];
#pragma unroll
  for (int kk = 0; kk < 2; ++kk) {
    aofs[kk] = (wrb + l15) * 64 + (((kk * 4 + g) ^ (l15 & 7)) * 8);
    bofs[kk] = (wcb + l15) * 64 + (((kk * 4 + g) ^ (l15 & 7)) * 8);
  }

  float bestV[4][4], secV[4][4];
  int bestI[4][4];
#pragma unroll
  for (int m = 0; m < 4; ++m)
#pragma unroll
    for (int r = 0; r < 4; ++r) {
      bestV[m][r] = 3.4e38f; secV[m][r] = 3.4e38f; bestI[m][r] = 0;
    }

  f32x4 acc[4][4];
#pragma unroll
  for (int m = 0; m < 4; ++m)
#pragma unroll
    for (int n = 0; n < 4; ++n) acc[m][n] = (f32x4)0.f;

#define ISSUE(ct_, kc_, buf_)                                            \
  {                                                                      \
    const u16* as_ = Xh + asrc + (kc_) * 64;                             \
    const u16* bs_ = Wthi + (size_t)(ct_) * 128 * ND + bsrc + (kc_) * 64;\
    u16* ad_ = Ah + (buf_) * 8192 + w * 32 * 64;                         \
    u16* bd_ = Bh + (buf_) * 8192 + w * 32 * 64;                         \
    _Pragma("unroll")                                                    \
    for (int q = 0; q < 4; ++q) {                                        \
      gl_lds16(as_ + (size_t)(q * 8) * ND, ad_ + q * 8 * 64);            \
      gl_lds16(bs_ + (size_t)(q * 8) * ND, bd_ + q * 8 * 64);            \
    }                                                                    \
  }

  // prologue: issue steps 0 and 1; wait for step 0 (8 newest stay in flight)
  ISSUE(0, 0, 0);
  ISSUE(0, 1, 1);
  asm volatile("s_waitcnt vmcnt(8) lgkmcnt(0)" ::: "memory");
  __builtin_amdgcn_sched_barrier(0);
  __builtin_amdgcn_s_barrier();
  __builtin_amdgcn_sched_barrier(0);

  int bc = 0;   // compute-buffer index for step s
  for (int s = 0; s < 64; ++s) {
    const int kc = s & 7;
    if (s + 2 < 64) {
      const int ns = s + 2;
      int nb = bc + 2; if (nb >= 3) nb -= 3;
      ISSUE(ns >> 3, ns & 7, nb);
    }
    const u16* Ab = Ah + bc * 8192;
    const u16* Bb = Bh + bc * 8192;
#pragma unroll
    for (int kk = 0; kk < 2; ++kk) {
      half8v a_h[4];
#pragma unroll
      for (int m = 0; m < 4; ++m)
        a_h[m] = *(const half8v*)&Ab[aofs[kk] + m * 1024];
#pragma unroll
      for (int n = 0; n < 4; ++n) {
        half8v b_h = *(const half8v*)&Bb[bofs[kk] + n * 1024];
#pragma unroll
        for (int m = 0; m < 4; ++m)
          acc[m][n] = mfma16f(a_h[m], b_h, acc[m][n]);
      }
    }
    if (kc == 7) {
      const int ct = s >> 3;
      // epilogue for ct. C layout: col = 16n + l15, row = 16m + 4g + r
#pragma unroll
      for (int n = 0; n < 4; ++n) {
        int col = ct * 128 + wcb + 16 * n + l15;
        float wq = wsq_s[col];
#pragma unroll
        for (int m = 0; m < 4; ++m)
#pragma unroll
          for (int r = 0; r < 4; ++r) {
            float v = wq - 2.0f * acc[m][n][r];
            if (v < bestV[m][r]) {
              secV[m][r] = bestV[m][r];
              bestV[m][r] = v;
              bestI[m][r] = col;
            } else if (v < secV[m][r]) {
              secV[m][r] = v;
            }
          }
      }
#pragma unroll
      for (int m = 0; m < 4; ++m)
#pragma unroll
        for (int n = 0; n < 4; ++n) acc[m][n] = (f32x4)0.f;
    }
    // counted wait: keep the just-issued step (s+2) in flight; require s+1
    if (s < 62)
      asm volatile("s_waitcnt vmcnt(8)" ::: "memory");
    else if (s == 62)
      asm volatile("s_waitcnt vmcnt(0)" ::: "memory");
    __builtin_amdgcn_sched_barrier(0);
    __builtin_amdgcn_s_barrier();
    __builtin_amdgcn_sched_barrier(0);
    bc = (bc + 1 == 3) ? 0 : bc + 1;
  }
#undef ISSUE

  // cross-lane reduce: 16 lanes share each row; merge (b1,idx,b2)
#pragma unroll
  for (int m = 0; m < 4; ++m)
#pragma unroll
    for (int r = 0; r < 4; ++r) {
      float v = bestV[m][r];
      float sec = secV[m][r];
      int idx = bestI[m][r];
#pragma unroll
      for (int mask = 1; mask < 16; mask <<= 1) {
        float ov = __shfl_xor(v, mask, 64);
        float os = __shfl_xor(sec, mask, 64);
        int oi = __shfl_xor(idx, mask, 64);
        float nsec = fminf(fminf(sec, os), fmaxf(v, ov));
        if (ov < v || (ov == v && oi < idx)) { v = ov; idx = oi; }
        sec = nsec;
      }
      if (l15 == 0) {
        int rowl = wrb + 16 * m + 4 * g + r;
        redV[rowl][w & 1] = v;
        redS[rowl][w & 1] = sec;
        redI[rowl][w & 1] = idx;
      }
    }
  __syncthreads();
  if (t < 128) {
    float v0 = redV[t][0], v1 = redV[t][1];
    float s0 = redS[t][0], s1 = redS[t][1];
    int i0 = redI[t][0], i1 = redI[t][1];
    float bv, sec;
    int bi;
    if (v1 < v0 || (v1 == v0 && i1 < i0)) { bv = v1; bi = i1; }
    else { bv = v0; bi = i0; }
    sec = fminf(fminf(s0, s1), fmaxf(v0, v1));
    int b = brow + t;
    argmin_i[b] = bi;
    argmin_f[b] = (float)bi;
    atomicAdd(&counts[bi], 1);
    atomicAdd(&bhist[(size_t)bi * NC + cls[b]], 1.0f);
    if (sec - bv < TAU) {
      int slot = atomicAdd(flagCnt, 1);
      if (slot < FLAG_CAP) flagList[slot] = b;
    }
  }
}

// -------- kernel 3a: exact f32 rescore, 8 rows x all 1024 k per block -------
__global__ __launch_bounds__(256) void fixup_score(
    const float* __restrict__ X, const float* __restrict__ Wt32,
    const float* __restrict__ wsq, const int* __restrict__ flagCnt,
    const int* __restrict__ flagList, u64* __restrict__ fkeys) {
  __shared__ float xs[FROWS][ND];
  __shared__ int rows[FROWS];
  __shared__ u64 wred[4][FROWS];
  int n = *flagCnt;
  if (n > FLAG_CAP) n = FLAG_CAP;
  int r0 = blockIdx.x * FROWS;
  if (r0 >= n) return;
  int nr = n - r0; if (nr > FROWS) nr = FROWS;
  int t = threadIdx.x;
  if (t < FROWS) rows[t] = flagList[r0 + (t < nr ? t : 0)];
  __syncthreads();
  for (int j = t; j < FROWS * (ND / 4); j += 256) {
    int r = j >> 7, c = j & 127;
    ((float4*)xs[r])[c] = ((const float4*)(X + (size_t)rows[r] * ND))[c];
  }
  __syncthreads();

  const int k0 = t * 4;
  const float4* w0 = (const float4*)(Wt32 + (size_t)(k0 + 0) * ND);
  const float4* w1 = (const float4*)(Wt32 + (size_t)(k0 + 1) * ND);
  const float4* w2 = (const float4*)(Wt32 + (size_t)(k0 + 2) * ND);
  const float4* w3 = (const float4*)(Wt32 + (size_t)(k0 + 3) * ND);
  float a[4][FROWS];
#pragma unroll
  for (int kk = 0; kk < 4; ++kk)
#pragma unroll
    for (int r = 0; r < FROWS; ++r) a[kk][r] = 0.f;

  for (int d = 0; d < ND / 4; ++d) {
    float4 v0 = w0[d], v1 = w1[d], v2 = w2[d], v3 = w3[d];
#pragma unroll
    for (int r = 0; r < FROWS; ++r) {
      float4 x4 = ((const float4*)xs[r])[d];
      a[0][r] += x4.x * v0.x + x4.y * v0.y + x4.z * v0.z + x4.w * v0.w;
      a[1][r] += x4.x * v1.x + x4.y * v1.y + x4.z * v1.z + x4.w * v1.w;
      a[2][r] += x4.x * v2.x + x4.y * v2.y + x4.z * v2.z + x4.w * v2.w;
      a[3][r] += x4.x * v3.x + x4.y * v3.y + x4.z * v3.z + x4.w * v3.w;
    }
  }

  float wq0 = wsq[k0], wq1 = wsq[k0 + 1], wq2 = wsq[k0 + 2], wq3 = wsq[k0 + 3];
  const int wv_ = t >> 6, lane = t & 63;
#pragma unroll
  for (int r = 0; r < FROWS; ++r) {
    float bv = wq0 - 2.0f * a[0][r];
    int bk = k0;
    float v;
    v = wq1 - 2.0f * a[1][r]; if (v < bv) { bv = v; bk = k0 + 1; }
    v = wq2 - 2.0f * a[2][r]; if (v < bv) { bv = v; bk = k0 + 2; }
    v = wq3 - 2.0f * a[3][r]; if (v < bv) { bv = v; bk = k0 + 3; }
    u64 key = ((u64)f32_sortable(bv) << 32) | (u32)bk;
#pragma unroll
    for (int m = 1; m < 64; m <<= 1) {
      u64 o = __shfl_xor(key, m, 64);
      if (o < key) key = o;
    }
    if (lane == 0) wred[wv_][r] = key;
  }
  __syncthreads();
  if (t < nr) {
    u64 k = wred[0][t];
    if (wred[1][t] < k) k = wred[1][t];
    if (wred[2][t] < k) k = wred[2][t];
    if (wred[3][t] < k) k = wred[3][t];
    fkeys[r0 + t] = k;
  }
}

// -------- kernel 3b: apply rescored winners -----------
__global__ __launch_bounds__(256) void fixup_apply(
    const int* __restrict__ flagCnt, const int* __restrict__ flagList,
    const u64* __restrict__ fkeys, const int* __restrict__ cls,
    int* __restrict__ argmin_i, float* __restrict__ argmin_f,
    int* __restrict__ counts, float* __restrict__ bhist) {
  int n = *flagCnt;
  if (n > FLAG_CAP) n = FLAG_CAP;
  int s = blockIdx.x * 256 + threadIdx.x;
  if (s >= n) return;
  int row = flagList[s];
  int nk = (int)(u32)(fkeys[s] & 0xffffffffu);
  int old = argmin_i[row];
  if (nk != old) {
    argmin_i[row] = nk;
    argmin_f[row] = (float)nk;
    atomicSub(&counts[old], 1);
    atomicAdd(&counts[nk], 1);
    int c = cls[row];
    atomicAdd(&bhist[(size_t)old * NC + c], -1.0f);
    atomicAdd(&bhist[(size_t)nk * NC + c], 1.0f);
  }
}

// -------- kernel 4: scan + cluster_size EMA + cs_norm -------
__global__ __launch_bounds__(1024) void scan_kernel(
    const int* __restrict__ counts, const float* __restrict__ cluster_size,
    float* __restrict__ out_ncs, float* __restrict__ csnorm,
    int* __restrict__ offsets) {
  __shared__ float wsum[16];
  __shared__ int wcnt[16];
  int t = threadIdx.x, lane = t & 63, wv = t >> 6;
  int cnt = counts[t];
  float ncs = cluster_size[t] * 0.99f + 0.01f * (cnt == 0 ? 1.0f : (float)cnt);
  out_ncs[t] = ncs;

  float s = ncs;
#pragma unroll
  for (int m = 1; m < 64; m <<= 1) s += __shfl_xor(s, m, 64);
  int ic = cnt;
#pragma unroll
  for (int o = 1; o < 64; o <<= 1) {
    int v = __shfl_up(ic, o, 64);
    if (lane >= o) ic += v;
  }
  if (lane == 63) { wsum[wv] = s; wcnt[wv] = ic; }
  __syncthreads();
  float n = 0.f;
  int coff = 0;
  for (int i = 0; i < 16; ++i) {
    n += wsum[i];
    if (i < wv) coff += wcnt[i];
  }
  csnorm[t] = (ncs + 1e-5f) / (n + 1024.0f * 1e-5f) * n;
  offsets[t] = coff + ic - cnt;
}

// --------- kernel 5: reorder rows by cluster (also writes korder) -----------
__global__ __launch_bounds__(256) void reorder_kernel(
    const int* __restrict__ argmin_i, const int* __restrict__ offsets,
    int* __restrict__ cursor, int* __restrict__ order,
    int* __restrict__ korder) {
  int b = blockIdx.x * 256 + threadIdx.x;
  int k = argmin_i[b];
  int pos = atomicAdd(&cursor[k], 1);
  int o = offsets[k] + pos;
  order[o] = b;
  korder[o] = k;
}

// -------- kernel 6: balanced chunk-scan gather with run-boundary atomics ----
__global__ __launch_bounds__(256) void gather_runs(
    const float* __restrict__ X, const int* __restrict__ order,
    const int* __restrict__ korder, float* __restrict__ esum) {
  __shared__ int so[GROWS];
  __shared__ int sk[GROWS];
  int t = threadIdx.x;
  int base = blockIdx.x * GROWS;
  if (t < GROWS) {
    so[t] = order[base + t];
    sk[t] = korder[base + t];
  }
  __syncthreads();
  float a0 = 0.f, a1 = 0.f;
  int curk = sk[0];
#pragma unroll 8
  for (int m = 0; m < GROWS; ++m) {
    int k = sk[m];
    if (k != curk) {   // uniform across block
      atomicAdd(&esum[(size_t)curk * ND + 2 * t], a0);
      atomicAdd(&esum[(size_t)curk * ND + 2 * t + 1], a1);
      a0 = 0.f; a1 = 0.f; curk = k;
    }
    float2 v = *(const float2*)(X + (size_t)so[m] * ND + 2 * t);
    a0 += v.x;
    a1 += v.y;
  }
  atomicAdd(&esum[(size_t)curk * ND + 2 * t], a0);
  atomicAdd(&esum[(size_t)curk * ND + 2 * t + 1], a1);
}

// ------- kernel 7: embed_avg EMA + weight (transpose) --------
__global__ __launch_bounds__(256) void ema_embed_kernel(
    const float* __restrict__ esum, const float* __restrict__ embed_avg,
    const float* __restrict__ csnorm, float* __restrict__ out_w,
    float* __restrict__ out_ea) {
  __shared__ float tile[32][33];
  int kb = blockIdx.x & 31;
  int db = blockIdx.x >> 5;
  int tx = threadIdx.x & 31, ty = threadIdx.x >> 5;
#pragma unroll
  for (int i = 0; i < 4; ++i) {
    int kl = ty + i * 8;
    tile[kl][tx] = esum[(size_t)(kb * 32 + kl) * ND + db * 32 + tx];
  }
  __syncthreads();
#pragma unroll
  for (int i = 0; i < 4; ++i) {
    int d = db * 32 + ty + i * 8;
    int k = kb * 32 + tx;
    size_t idx = (size_t)d * NK + k;
    float nea = embed_avg[idx] * 0.99f + 0.01f * tile[tx][ty + i * 8];
    out_ea[idx] = nea;
    out_w[idx] = nea / csnorm[k];
  }
}

// ---------------- kernel 8: hist EMA ----------------
__global__ __launch_bounds__(256) void hist_kernel(const float* __restrict__ hist,
                                                   const float* __restrict__ bhist,
                                                   float* __restrict__ out_hist) {
  int i = blockIdx.x * 256 + threadIdx.x;
  out_hist[i] = hist[i] * 0.99f + 0.01f * bhist[i];
}

extern "C" void kernel_launch(void* const* d_in, const int* in_sizes, int n_in,
                              void* d_out, int out_size, void* d_ws, size_t ws_size,
                              hipStream_t stream) {
  const float* X = (const float*)d_in[0];
  const int* cls = (const int*)d_in[1];
  const float* W = (const float*)d_in[2];
  const float* cluster_size = (const float*)d_in[3];
  const float* embed_avg = (const float*)d_in[4];
  const float* hist = (const float*)d_in[5];

  float* wsf = (float*)d_ws;
  int* wsi = (int*)d_ws;
  int* counts = wsi + OFF_COUNTS;
  int* cursor = wsi + OFF_CURSOR;
  float* bhist = wsf + OFF_BHIST;
  int* flagCnt = wsi + OFF_FLAGCNT;
  float* wsq = wsf + OFF_WSQ;
  int* flagList = wsi + OFF_FLAGLIST;
  u64* fkeys = (u64*)(wsf + OFF_FKEYS);
  float* csnorm = wsf + OFF_CSNORM;
  int* offsets = wsi + OFF_OFFSETS;
  int* argmin_i = wsi + OFF_ARGMIN;
  int* order = wsi + OFF_ORDER;
  int* korder = wsi + OFF_KORDER;
  u16* Wthi = (u16*)(wsf + OFF_WTHI);
  float* Wt32 = wsf + OFF_WT32;
  u16* Xh = (u16*)(wsf + OFF_XH);
  float* esum = wsf + OFF_ESUM;

  float* out = (float*)d_out;
  float* out_w = out;
  float* out_ncs = out + (size_t)ND * NK;
  float* out_ea = out_ncs + NK;
  float* out_hist = out_ea + (size_t)ND * NK;
  float* out_arg = out_hist + (size_t)NK * NC;

  hipMemsetAsync(d_ws, 0, (size_t)OFF_ZERO_END * 4, stream);
  hipMemsetAsync(esum, 0, (size_t)NK * ND * 4, stream);

  prep_w<<<512, 256, 0, stream>>>(W, Wthi, Wt32, wsq);
  prep_x<<<NB * ND / 8 / 256, 256, 0, stream>>>(X, Xh);
  argmin_tri<<<NB / 128, 256, 0, stream>>>(Xh, Wthi, wsq, cls, argmin_i,
                                           out_arg, counts, bhist, flagCnt,
                                           flagList);
  fixup_score<<<FLAG_CAP / FROWS, 256, 0, stream>>>(X, Wt32, wsq, flagCnt,
                                                    flagList, fkeys);
  fixup_apply<<<FLAG_CAP / 256, 256, 0, stream>>>(flagCnt, flagList, fkeys, cls,
                                                  argmin_i, out_arg, counts,
                                                  bhist);
  scan_kernel<<<1, 1024, 0, stream>>>(counts, cluster_size, out_ncs, csnorm,
                                      offsets);
  reorder_kernel<<<NB / 256, 256, 0, stream>>>(argmin_i, offsets, cursor, order,
                                               korder);
  gather_runs<<<NB / GROWS, 256, 0, stream>>>(X, order, korder, esum);
  ema_embed_kernel<<<(NK / 32) * (ND / 32), 256, 0, stream>>>(
      esum, embed_avg, csnorm, out_w, out_ea);
  hist_kernel<<<(NK * NC) / 256, 256, 0, stream>>>(hist, bhist, out_hist);
}

// Round 16
// 369.228 us; speedup vs baseline: 1.3052x; 1.3052x over previous
//
#include <hip/hip_runtime.h>
#include <hip/hip_fp16.h>

// clusteringEMA: B=65536, D=512, K=1024, C=100
// R16: r12 streaming argmin with 256-col ct passes (4 instead of 8) to halve
// the A-slab re-read. A: BK=64 conflict-free chunks (dbuf, gl_lds16), each
// stage feeds 2 steps (kk=0/1). B: 256x32 tiles (16KB, dbuf, gl_lds16).
// LDS = 72704 B == r12 -> 2 blocks/CU (the session's proven requirement).
// Tail kernels identical to r12/r15.

#define NB 65536
#define ND 512
#define NK 1024
#define NC 100
#define TAU 0.25f
#define FLAG_CAP 16384
#define FROWS 8
#define GROWS 128

typedef unsigned int u32;
typedef unsigned short u16;
typedef unsigned long long u64;
typedef __attribute__((ext_vector_type(8))) _Float16 half8v;
typedef __attribute__((ext_vector_type(4))) float f32x4;

// ---------------- ws layout (4-byte units) ----------------
#define OFF_COUNTS   0          // int [1024]
#define OFF_CURSOR   1024       // int [1024]
#define OFF_BHIST    2048       // float [102400]
#define OFF_FLAGCNT  104448     // int [64]
#define OFF_WSQ      104512     // float [1024]
#define OFF_ZERO_END 105536
#define OFF_FLAGLIST 105536     // int [16384]
#define OFF_FKEYS    121920     // u64 [16384]
#define OFF_CSNORM   154688     // float [1024]
#define OFF_OFFSETS  155712     // int [1024]
#define OFF_ARGMIN   156736     // int [65536]
#define OFF_ORDER    222272     // int [65536]
#define OFF_KORDER   287808     // int [65536]
#define OFF_WTHI     353344     // u16 [524288] = 262144 float slots
#define OFF_WT32     615488     // float [524288]
#define OFF_XH       1139776    // u16 [33554432] = 16777216 float slots
#define OFF_ESUM     17916992   // float [524288]

__device__ inline f32x4 mfma16f(half8v a, half8v b, f32x4 c) {
  return __builtin_amdgcn_mfma_f32_16x16x32_f16(a, b, c, 0, 0, 0);
}

__device__ __forceinline__ void gl_lds16(const u16* g, u16* l) {
  __builtin_amdgcn_global_load_lds(
      (const __attribute__((address_space(1))) u32*)g,
      (__attribute__((address_space(3))) u32*)l, 16, 0, 0);
}

__device__ inline u32 f32_sortable(float f) {
  u32 b = __float_as_uint(f);
  return (b & 0x80000000u) ? ~b : (b | 0x80000000u);
}

__device__ inline half8v cvt8_f16(const float4& a, const float4& b) {
  half8v h;
  h[0] = (_Float16)a.x; h[1] = (_Float16)a.y;
  h[2] = (_Float16)a.z; h[3] = (_Float16)a.w;
  h[4] = (_Float16)b.x; h[5] = (_Float16)b.y;
  h[6] = (_Float16)b.z; h[7] = (_Float16)b.w;
  return h;
}

// ------ kernel 0: X -> Xh (f16 RNE), one pass ------
__global__ __launch_bounds__(256) void prep_x(const float* __restrict__ X,
                                              u16* __restrict__ Xh) {
  size_t i = ((size_t)blockIdx.x * 256 + threadIdx.x) * 8;
  float4 a = *(const float4*)(X + i);
  float4 b = *(const float4*)(X + i + 4);
  *(half8v*)(Xh + i) = cvt8_f16(a, b);
}

// ------ kernel 1: W -> Wt (transposed; f16 RNE + f32) + wsq ------
__global__ __launch_bounds__(256) void prep_w(const float* __restrict__ W,
                                              u16* __restrict__ Wthi,
                                              float* __restrict__ Wt32,
                                              float* __restrict__ wsq) {
  __shared__ float tile[32][33];
  int db = blockIdx.x & 15;
  int kb = blockIdx.x >> 4;
  int tx = threadIdx.x & 31, ty = threadIdx.x >> 5;
  float s = 0.f;
#pragma unroll
  for (int i = 0; i < 4; ++i) {
    int d = db * 32 + ty + 8 * i;
    float wv = W[(size_t)d * NK + kb * 32 + tx];
    tile[ty + 8 * i][tx] = wv;
    s += wv * wv;
  }
  atomicAdd(&wsq[kb * 32 + tx], s);
  __syncthreads();
#pragma unroll
  for (int i = 0; i < 4; ++i) {
    int kl = ty + 8 * i;
    float f = tile[tx][kl];
    size_t o = (size_t)(kb * 32 + kl) * ND + db * 32 + tx;
    Wt32[o] = f;
    Wthi[o] = __half_as_ushort(__float2half(f));
  }
}

// --- kernel 2: argmin MFMA, 256-col ct passes, dbuf A(BK=64) + B(256x32) ----
__global__ __launch_bounds__(256, 2) void argmin_pair(
    const u16* __restrict__ Xh, const u16* __restrict__ Wthi,
    const float* __restrict__ wsq, const int* __restrict__ cls,
    int* __restrict__ argmin_i, float* __restrict__ argmin_f,
    int* __restrict__ counts, float* __restrict__ bhist,
    int* __restrict__ flagCnt, int* __restrict__ flagList) {
  __shared__ __align__(16) u16 Ah[2 * 128 * 64];   // 2 x 16KB (BK=64 chunks)
  __shared__ __align__(16) u16 Bh[2 * 256 * 32];   // 2 x 16KB (256 cols x 32d)
  __shared__ float wsq_s[NK];                      // 4KB
  __shared__ float redV[128][2];
  __shared__ float redS[128][2];
  __shared__ int redI[128][2];                     // total 72704 B

  const int t = threadIdx.x;
  const int lane = t & 63;
  const int w = t >> 6;
  const int g = lane >> 4;
  const int l15 = lane & 15;
  const int wrb = (w >> 1) * 64;    // wave row base
  const int wcb = (w & 1) * 128;    // wave col base within the 256-col tile
  const int brow = blockIdx.x * 128;

#pragma unroll
  for (int i = 0; i < 4; ++i) wsq_s[t + 256 * i] = wsq[t + 256 * i];

  // A staging (r12 map, conflict-free): lane -> row sub = lane>>3, phys chunk
  // c8p = lane&7; source chunk = c8p ^ sub
  const int sub = lane >> 3;
  const int c8p = lane & 7;
  const size_t asrc = (size_t)(brow + w * 32 + sub) * ND + (size_t)((c8p ^ sub) * 8);

  // B staging (256x32 tile): lane -> row-in-16 rp = lane>>2, phys chunk
  // lane&3; source chunk = (lane&3) ^ (rp&3)
  const int rp = lane >> 2;
  const int bcl = (lane & 3) ^ (rp & 3);
  const size_t bsrc = (size_t)(w * 64 + rp) * ND + (size_t)(bcl * 8);

  // fragment read offsets (u16 units)
  int aofs[2];
#pragma unroll
  for (int kk = 0; kk < 2; ++kk)
    aofs[kk] = (wrb + l15) * 64 + (((kk * 4 + g) ^ (l15 & 7)) * 8);
  const int bofs = (wcb + l15) * 32 + ((g ^ (l15 & 3)) * 8);

  float bestV[4][4], secV[4][4];
  int bestI[4][4];
#pragma unroll
  for (int m = 0; m < 4; ++m)
#pragma unroll
    for (int r = 0; r < 4; ++r) {
      bestV[m][r] = 3.4e38f; secV[m][r] = 3.4e38f; bestI[m][r] = 0;
    }

  f32x4 acc[4][8];
#pragma unroll
  for (int m = 0; m < 4; ++m)
#pragma unroll
    for (int n = 0; n < 8; ++n) acc[m][n] = (f32x4)0.f;

#define ISSUE_A(kc_, ab_)                                                \
  {                                                                      \
    const u16* as_ = Xh + asrc + (kc_) * 64;                             \
    u16* ad_ = Ah + (ab_) * 8192 + w * 32 * 64;                          \
    _Pragma("unroll")                                                    \
    for (int q = 0; q < 4; ++q)                                          \
      gl_lds16(as_ + (size_t)(q * 8) * ND, ad_ + q * 8 * 64);            \
  }
#define ISSUE_B(ct_, sk_, bb_)                                           \
  {                                                                      \
    const u16* bs_ = Wthi + (size_t)(ct_) * 256 * ND + bsrc + (sk_) * 32;\
    u16* bd_ = Bh + (bb_) * 8192 + w * 64 * 32;                          \
    _Pragma("unroll")                                                    \
    for (int q = 0; q < 4; ++q)                                          \
      gl_lds16(bs_ + (size_t)(q * 16) * ND, bd_ + q * 16 * 32);          \
  }
#define DRAIN asm volatile("s_waitcnt vmcnt(0) lgkmcnt(0)" ::: "memory")

  ISSUE_A(0, 0);
  ISSUE_B(0, 0, 0);
  DRAIN;
  __syncthreads();

  for (int s = 0; s < 64; ++s) {
    const int sk = s & 15;          // sub-step within ct (32 d each)
    const int kpar = s & 1;         // which kk half of the A chunk
    const int abuf = (s >> 1) & 1;
    const int bbuf = s & 1;
    if (s < 63) {
      const int s1 = s + 1;
      ISSUE_B(s1 >> 4, s1 & 15, s1 & 1);
      if (s & 1) ISSUE_A(((s1 & 15) >> 1), (s1 >> 1) & 1);
    }
    const u16* Ab = Ah + abuf * 8192;
    const u16* Bb = Bh + bbuf * 8192;
    {
      half8v a_h[4];
#pragma unroll
      for (int m = 0; m < 4; ++m)
        a_h[m] = *(const half8v*)&Ab[aofs[kpar] + m * 1024];
#pragma unroll
      for (int n = 0; n < 8; ++n) {
        half8v b_h = *(const half8v*)&Bb[bofs + n * 512];
#pragma unroll
        for (int m = 0; m < 4; ++m)
          acc[m][n] = mfma16f(a_h[m], b_h, acc[m][n]);
      }
    }
    if (sk == 15) {
      const int ct = s >> 4;
      // epilogue for ct. C layout: col = 16n + l15, row = 16m + 4g + r
#pragma unroll
      for (int n = 0; n < 8; ++n) {
        int col = ct * 256 + wcb + 16 * n + l15;
        float wq = wsq_s[col];
#pragma unroll
        for (int m = 0; m < 4; ++m)
#pragma unroll
          for (int r = 0; r < 4; ++r) {
            float v = wq - 2.0f * acc[m][n][r];
            if (v < bestV[m][r]) {
              secV[m][r] = bestV[m][r];
              bestV[m][r] = v;
              bestI[m][r] = col;
            } else if (v < secV[m][r]) {
              secV[m][r] = v;
            }
          }
      }
#pragma unroll
      for (int m = 0; m < 4; ++m)
#pragma unroll
        for (int n = 0; n < 8; ++n) acc[m][n] = (f32x4)0.f;
    }
    DRAIN;             // next-step tiles landed (issued before compute)
    __syncthreads();
  }
#undef ISSUE_A
#undef ISSUE_B
#undef DRAIN

  // cross-lane reduce: 16 lanes share each row; merge (b1,idx,b2)
#pragma unroll
  for (int m = 0; m < 4; ++m)
#pragma unroll
    for (int r = 0; r < 4; ++r) {
      float v = bestV[m][r];
      float sec = secV[m][r];
      int idx = bestI[m][r];
#pragma unroll
      for (int mask = 1; mask < 16; mask <<= 1) {
        float ov = __shfl_xor(v, mask, 64);
        float os = __shfl_xor(sec, mask, 64);
        int oi = __shfl_xor(idx, mask, 64);
        float nsec = fminf(fminf(sec, os), fmaxf(v, ov));
        if (ov < v || (ov == v && oi < idx)) { v = ov; idx = oi; }
        sec = nsec;
      }
      if (l15 == 0) {
        int rowl = wrb + 16 * m + 4 * g + r;
        redV[rowl][w & 1] = v;
        redS[rowl][w & 1] = sec;
        redI[rowl][w & 1] = idx;
      }
    }
  __syncthreads();
  if (t < 128) {
    float v0 = redV[t][0], v1 = redV[t][1];
    float s0 = redS[t][0], s1 = redS[t][1];
    int i0 = redI[t][0], i1 = redI[t][1];
    float bv, sec;
    int bi;
    if (v1 < v0 || (v1 == v0 && i1 < i0)) { bv = v1; bi = i1; }
    else { bv = v0; bi = i0; }
    sec = fminf(fminf(s0, s1), fmaxf(v0, v1));
    int b = brow + t;
    argmin_i[b] = bi;
    argmin_f[b] = (float)bi;
    atomicAdd(&counts[bi], 1);
    atomicAdd(&bhist[(size_t)bi * NC + cls[b]], 1.0f);
    if (sec - bv < TAU) {
      int slot = atomicAdd(flagCnt, 1);
      if (slot < FLAG_CAP) flagList[slot] = b;
    }
  }
}

// -------- kernel 3a: exact f32 rescore, 8 rows x all 1024 k per block -------
__global__ __launch_bounds__(256) void fixup_score(
    const float* __restrict__ X, const float* __restrict__ Wt32,
    const float* __restrict__ wsq, const int* __restrict__ flagCnt,
    const int* __restrict__ flagList, u64* __restrict__ fkeys) {
  __shared__ float xs[FROWS][ND];
  __shared__ int rows[FROWS];
  __shared__ u64 wred[4][FROWS];
  int n = *flagCnt;
  if (n > FLAG_CAP) n = FLAG_CAP;
  int r0 = blockIdx.x * FROWS;
  if (r0 >= n) return;
  int nr = n - r0; if (nr > FROWS) nr = FROWS;
  int t = threadIdx.x;
  if (t < FROWS) rows[t] = flagList[r0 + (t < nr ? t : 0)];
  __syncthreads();
  for (int j = t; j < FROWS * (ND / 4); j += 256) {
    int r = j >> 7, c = j & 127;
    ((float4*)xs[r])[c] = ((const float4*)(X + (size_t)rows[r] * ND))[c];
  }
  __syncthreads();

  const int k0 = t * 4;
  const float4* w0 = (const float4*)(Wt32 + (size_t)(k0 + 0) * ND);
  const float4* w1 = (const float4*)(Wt32 + (size_t)(k0 + 1) * ND);
  const float4* w2 = (const float4*)(Wt32 + (size_t)(k0 + 2) * ND);
  const float4* w3 = (const float4*)(Wt32 + (size_t)(k0 + 3) * ND);
  float a[4][FROWS];
#pragma unroll
  for (int kk = 0; kk < 4; ++kk)
#pragma unroll
    for (int r = 0; r < FROWS; ++r) a[kk][r] = 0.f;

  for (int d = 0; d < ND / 4; ++d) {
    float4 v0 = w0[d], v1 = w1[d], v2 = w2[d], v3 = w3[d];
#pragma unroll
    for (int r = 0; r < FROWS; ++r) {
      float4 x4 = ((const float4*)xs[r])[d];
      a[0][r] += x4.x * v0.x + x4.y * v0.y + x4.z * v0.z + x4.w * v0.w;
      a[1][r] += x4.x * v1.x + x4.y * v1.y + x4.z * v1.z + x4.w * v1.w;
      a[2][r] += x4.x * v2.x + x4.y * v2.y + x4.z * v2.z + x4.w * v2.w;
      a[3][r] += x4.x * v3.x + x4.y * v3.y + x4.z * v3.z + x4.w * v3.w;
    }
  }

  float wq0 = wsq[k0], wq1 = wsq[k0 + 1], wq2 = wsq[k0 + 2], wq3 = wsq[k0 + 3];
  const int wv_ = t >> 6, lane = t & 63;
#pragma unroll
  for (int r = 0; r < FROWS; ++r) {
    float bv = wq0 - 2.0f * a[0][r];
    int bk = k0;
    float v;
    v = wq1 - 2.0f * a[1][r]; if (v < bv) { bv = v; bk = k0 + 1; }
    v = wq2 - 2.0f * a[2][r]; if (v < bv) { bv = v; bk = k0 + 2; }
    v = wq3 - 2.0f * a[3][r]; if (v < bv) { bv = v; bk = k0 + 3; }
    u64 key = ((u64)f32_sortable(bv) << 32) | (u32)bk;
#pragma unroll
    for (int m = 1; m < 64; m <<= 1) {
      u64 o = __shfl_xor(key, m, 64);
      if (o < key) key = o;
    }
    if (lane == 0) wred[wv_][r] = key;
  }
  __syncthreads();
  if (t < nr) {
    u64 k = wred[0][t];
    if (wred[1][t] < k) k = wred[1][t];
    if (wred[2][t] < k) k = wred[2][t];
    if (wred[3][t] < k) k = wred[3][t];
    fkeys[r0 + t] = k;
  }
}

// -------- kernel 3b: apply rescored winners -----------
__global__ __launch_bounds__(256) void fixup_apply(
    const int* __restrict__ flagCnt, const int* __restrict__ flagList,
    const u64* __restrict__ fkeys, const int* __restrict__ cls,
    int* __restrict__ argmin_i, float* __restrict__ argmin_f,
    int* __restrict__ counts, float* __restrict__ bhist) {
  int n = *flagCnt;
  if (n > FLAG_CAP) n = FLAG_CAP;
  int s = blockIdx.x * 256 + threadIdx.x;
  if (s >= n) return;
  int row = flagList[s];
  int nk = (int)(u32)(fkeys[s] & 0xffffffffu);
  int old = argmin_i[row];
  if (nk != old) {
    argmin_i[row] = nk;
    argmin_f[row] = (float)nk;
    atomicSub(&counts[old], 1);
    atomicAdd(&counts[nk], 1);
    int c = cls[row];
    atomicAdd(&bhist[(size_t)old * NC + c], -1.0f);
    atomicAdd(&bhist[(size_t)nk * NC + c], 1.0f);
  }
}

// -------- kernel 4: scan + cluster_size EMA + cs_norm -------
__global__ __launch_bounds__(1024) void scan_kernel(
    const int* __restrict__ counts, const float* __restrict__ cluster_size,
    float* __restrict__ out_ncs, float* __restrict__ csnorm,
    int* __restrict__ offsets) {
  __shared__ float wsum[16];
  __shared__ int wcnt[16];
  int t = threadIdx.x, lane = t & 63, wv = t >> 6;
  int cnt = counts[t];
  float ncs = cluster_size[t] * 0.99f + 0.01f * (cnt == 0 ? 1.0f : (float)cnt);
  out_ncs[t] = ncs;

  float s = ncs;
#pragma unroll
  for (int m = 1; m < 64; m <<= 1) s += __shfl_xor(s, m, 64);
  int ic = cnt;
#pragma unroll
  for (int o = 1; o < 64; o <<= 1) {
    int v = __shfl_up(ic, o, 64);
    if (lane >= o) ic += v;
  }
  if (lane == 63) { wsum[wv] = s; wcnt[wv] = ic; }
  __syncthreads();
  float n = 0.f;
  int coff = 0;
  for (int i = 0; i < 16; ++i) {
    n += wsum[i];
    if (i < wv) coff += wcnt[i];
  }
  csnorm[t] = (ncs + 1e-5f) / (n + 1024.0f * 1e-5f) * n;
  offsets[t] = coff + ic - cnt;
}

// --------- kernel 5: reorder rows by cluster (also writes korder) -----------
__global__ __launch_bounds__(256) void reorder_kernel(
    const int* __restrict__ argmin_i, const int* __restrict__ offsets,
    int* __restrict__ cursor, int* __restrict__ order,
    int* __restrict__ korder) {
  int b = blockIdx.x * 256 + threadIdx.x;
  int k = argmin_i[b];
  int pos = atomicAdd(&cursor[k], 1);
  int o = offsets[k] + pos;
  order[o] = b;
  korder[o] = k;
}

// -------- kernel 6: balanced chunk-scan gather with run-boundary atomics ----
__global__ __launch_bounds__(256) void gather_runs(
    const float* __restrict__ X, const int* __restrict__ order,
    const int* __restrict__ korder, float* __restrict__ esum) {
  __shared__ int so[GROWS];
  __shared__ int sk[GROWS];
  int t = threadIdx.x;
  int base = blockIdx.x * GROWS;
  if (t < GROWS) {
    so[t] = order[base + t];
    sk[t] = korder[base + t];
  }
  __syncthreads();
  float a0 = 0.f, a1 = 0.f;
  int curk = sk[0];
#pragma unroll 8
  for (int m = 0; m < GROWS; ++m) {
    int k = sk[m];
    if (k != curk) {   // uniform across block
      atomicAdd(&esum[(size_t)curk * ND + 2 * t], a0);
      atomicAdd(&esum[(size_t)curk * ND + 2 * t + 1], a1);
      a0 = 0.f; a1 = 0.f; curk = k;
    }
    float2 v = *(const float2*)(X + (size_t)so[m] * ND + 2 * t);
    a0 += v.x;
    a1 += v.y;
  }
  atomicAdd(&esum[(size_t)curk * ND + 2 * t], a0);
  atomicAdd(&esum[(size_t)curk * ND + 2 * t + 1], a1);
}

// ------- kernel 7: embed_avg EMA + weight (transpose) --------
__global__ __launch_bounds__(256) void ema_embed_kernel(
    const float* __restrict__ esum, const float* __restrict__ embed_avg,
    const float* __restrict__ csnorm, float* __restrict__ out_w,
    float* __restrict__ out_ea) {
  __shared__ float tile[32][33];
  int kb = blockIdx.x & 31;
  int db = blockIdx.x >> 5;
  int tx = threadIdx.x & 31, ty = threadIdx.x >> 5;
#pragma unroll
  for (int i = 0; i < 4; ++i) {
    int kl = ty + i * 8;
    tile[kl][tx] = esum[(size_t)(kb * 32 + kl) * ND + db * 32 + tx];
  }
  __syncthreads();
#pragma unroll
  for (int i = 0; i < 4; ++i) {
    int d = db * 32 + ty + i * 8;
    int k = kb * 32 + tx;
    size_t idx = (size_t)d * NK + k;
    float nea = embed_avg[idx] * 0.99f + 0.01f * tile[tx][ty + i * 8];
    out_ea[idx] = nea;
    out_w[idx] = nea / csnorm[k];
  }
}

// ---------------- kernel 8: hist EMA ----------------
__global__ __launch_bounds__(256) void hist_kernel(const float* __restrict__ hist,
                                                   const float* __restrict__ bhist,
                                                   float* __restrict__ out_hist) {
  int i = blockIdx.x * 256 + threadIdx.x;
  out_hist[i] = hist[i] * 0.99f + 0.01f * bhist[i];
}

extern "C" void kernel_launch(void* const* d_in, const int* in_sizes, int n_in,
                              void* d_out, int out_size, void* d_ws, size_t ws_size,
                              hipStream_t stream) {
  const float* X = (const float*)d_in[0];
  const int* cls = (const int*)d_in[1];
  const float* W = (const float*)d_in[2];
  const float* cluster_size = (const float*)d_in[3];
  const float* embed_avg = (const float*)d_in[4];
  const float* hist = (const float*)d_in[5];

  float* wsf = (float*)d_ws;
  int* wsi = (int*)d_ws;
  int* counts = wsi + OFF_COUNTS;
  int* cursor = wsi + OFF_CURSOR;
  float* bhist = wsf + OFF_BHIST;
  int* flagCnt = wsi + OFF_FLAGCNT;
  float* wsq = wsf + OFF_WSQ;
  int* flagList = wsi + OFF_FLAGLIST;
  u64* fkeys = (u64*)(wsf + OFF_FKEYS);
  float* csnorm = wsf + OFF_CSNORM;
  int* offsets = wsi + OFF_OFFSETS;
  int* argmin_i = wsi + OFF_ARGMIN;
  int* order = wsi + OFF_ORDER;
  int* korder = wsi + OFF_KORDER;
  u16* Wthi = (u16*)(wsf + OFF_WTHI);
  float* Wt32 = wsf + OFF_WT32;
  u16* Xh = (u16*)(wsf + OFF_XH);
  float* esum = wsf + OFF_ESUM;

  float* out = (float*)d_out;
  float* out_w = out;
  float* out_ncs = out + (size_t)ND * NK;
  float* out_ea = out_ncs + NK;
  float* out_hist = out_ea + (size_t)ND * NK;
  float* out_arg = out_hist + (size_t)NK * NC;

  hipMemsetAsync(d_ws, 0, (size_t)OFF_ZERO_END * 4, stream);
  hipMemsetAsync(esum, 0, (size_t)NK * ND * 4, stream);

  prep_w<<<512, 256, 0, stream>>>(W, Wthi, Wt32, wsq);
  prep_x<<<NB * ND / 8 / 256, 256, 0, stream>>>(X, Xh);
  argmin_pair<<<NB / 128, 256, 0, stream>>>(Xh, Wthi, wsq, cls, argmin_i,
                                            out_arg, counts, bhist, flagCnt,
                                            flagList);
  fixup_score<<<FLAG_CAP / FROWS, 256, 0, stream>>>(X, Wt32, wsq, flagCnt,
                                                    flagList, fkeys);
  fixup_apply<<<FLAG_CAP / 256, 256, 0, stream>>>(flagCnt, flagList, fkeys, cls,
                                                  argmin_i, out_arg, counts,
                                                  bhist);
  scan_kernel<<<1, 1024, 0, stream>>>(counts, cluster_size, out_ncs, csnorm,
                                      offsets);
  reorder_kernel<<<NB / 256, 256, 0, stream>>>(argmin_i, offsets, cursor, order,
                                               korder);
  gather_runs<<<NB / GROWS, 256, 0, stream>>>(X, order, korder, esum);
  ema_embed_kernel<<<(NK / 32) * (ND / 32), 256, 0, stream>>>(
      esum, embed_avg, csnorm, out_w, out_ea);
  hist_kernel<<<(NK * NC) / 256, 256, 0, stream>>>(hist, bhist, out_hist);
}

// Round 17
// 360.904 us; speedup vs baseline: 1.3353x; 1.0231x over previous
//
#include <hip/hip_runtime.h>
#include <hip/hip_fp16.h>

// clusteringEMA: B=65536, D=512, K=1024, C=100
// R17: (a) B tile re-laid as k-paired [128][64] (128B rows, 2-way banks ==
// free) killing r16's 4-way conflict; (b) tail fusions: prep_w+prep_x one
// kernel, fixup apply folded into score, esum zeroed in reorder, hist fused
// into ema. Launches 11 -> 7. A path / maps / numerics unchanged from r16.

#define NB 65536
#define ND 512
#define NK 1024
#define NC 100
#define TAU 0.25f
#define FLAG_CAP 16384
#define FROWS 8
#define GROWS 128

typedef unsigned int u32;
typedef unsigned short u16;
typedef unsigned long long u64;
typedef __attribute__((ext_vector_type(8))) _Float16 half8v;
typedef __attribute__((ext_vector_type(4))) float f32x4;

// ---------------- ws layout (4-byte units) ----------------
#define OFF_COUNTS   0          // int [1024]
#define OFF_CURSOR   1024       // int [1024]
#define OFF_BHIST    2048       // float [102400]
#define OFF_FLAGCNT  104448     // int [64]
#define OFF_WSQ      104512     // float [1024]
#define OFF_ZERO_END 105536
#define OFF_FLAGLIST 105536     // int [16384]
#define OFF_FKEYS    121920     // (unused, kept for layout stability)
#define OFF_CSNORM   154688     // float [1024]
#define OFF_OFFSETS  155712     // int [1024]
#define OFF_ARGMIN   156736     // int [65536]
#define OFF_ORDER    222272     // int [65536]
#define OFF_KORDER   287808     // int [65536]
#define OFF_WTHI     353344     // u16 [524288] = 262144 float slots
#define OFF_WT32     615488     // float [524288]
#define OFF_XH       1139776    // u16 [33554432] = 16777216 float slots
#define OFF_ESUM     17916992   // float [524288]

__device__ inline f32x4 mfma16f(half8v a, half8v b, f32x4 c) {
  return __builtin_amdgcn_mfma_f32_16x16x32_f16(a, b, c, 0, 0, 0);
}

__device__ __forceinline__ void gl_lds16(const u16* g, u16* l) {
  __builtin_amdgcn_global_load_lds(
      (const __attribute__((address_space(1))) u32*)g,
      (__attribute__((address_space(3))) u32*)l, 16, 0, 0);
}

__device__ inline u32 f32_sortable(float f) {
  u32 b = __float_as_uint(f);
  return (b & 0x80000000u) ? ~b : (b | 0x80000000u);
}

__device__ inline half8v cvt8_f16(const float4& a, const float4& b) {
  half8v h;
  h[0] = (_Float16)a.x; h[1] = (_Float16)a.y;
  h[2] = (_Float16)a.z; h[3] = (_Float16)a.w;
  h[4] = (_Float16)b.x; h[5] = (_Float16)b.y;
  h[6] = (_Float16)b.z; h[7] = (_Float16)b.w;
  return h;
}

// ------ kernel 1: fused prep: blocks [0,512) = W transpose+split+wsq;
//                  blocks [512, 512+16384) = X -> Xh f16 ------
__global__ __launch_bounds__(256) void prep_all(const float* __restrict__ W,
                                                const float* __restrict__ X,
                                                u16* __restrict__ Wthi,
                                                float* __restrict__ Wt32,
                                                u16* __restrict__ Xh,
                                                float* __restrict__ wsq) {
  __shared__ float tile[32][33];
  int t = threadIdx.x;
  if (blockIdx.x >= 512) {
    size_t i = ((size_t)(blockIdx.x - 512) * 256 + t) * 8;
    float4 a = *(const float4*)(X + i);
    float4 b = *(const float4*)(X + i + 4);
    *(half8v*)(Xh + i) = cvt8_f16(a, b);
    return;
  }
  int db = blockIdx.x & 15;
  int kb = blockIdx.x >> 4;
  int tx = t & 31, ty = t >> 5;
  float s = 0.f;
#pragma unroll
  for (int i = 0; i < 4; ++i) {
    int d = db * 32 + ty + 8 * i;
    float wv = W[(size_t)d * NK + kb * 32 + tx];
    tile[ty + 8 * i][tx] = wv;
    s += wv * wv;
  }
  atomicAdd(&wsq[kb * 32 + tx], s);
  __syncthreads();
#pragma unroll
  for (int i = 0; i < 4; ++i) {
    int kl = ty + 8 * i;
    float f = tile[tx][kl];
    size_t o = (size_t)(kb * 32 + kl) * ND + db * 32 + tx;
    Wt32[o] = f;
    Wthi[o] = __half_as_ushort(__float2half(f));
  }
}

// --- kernel 2: argmin MFMA, 256-col ct passes; B k-paired [128][64] layout --
__global__ __launch_bounds__(256, 2) void argmin_pair(
    const u16* __restrict__ Xh, const u16* __restrict__ Wthi,
    const float* __restrict__ wsq, const int* __restrict__ cls,
    int* __restrict__ argmin_i, float* __restrict__ argmin_f,
    int* __restrict__ counts, float* __restrict__ bhist,
    int* __restrict__ flagCnt, int* __restrict__ flagList) {
  __shared__ __align__(16) u16 Ah[2 * 128 * 64];   // 2 x 16KB (BK=64 chunks)
  __shared__ __align__(16) u16 Bh[2 * 128 * 64];   // 2 x 16KB (k-paired rows)
  __shared__ float wsq_s[NK];                      // 4KB
  __shared__ float redV[128][2];
  __shared__ float redS[128][2];
  __shared__ int redI[128][2];                     // total 72704 B

  const int t = threadIdx.x;
  const int lane = t & 63;
  const int w = t >> 6;
  const int g = lane >> 4;
  const int l15 = lane & 15;
  const int wrb = (w >> 1) * 64;    // wave row base
  const int wcb = (w & 1) * 128;    // wave col base within the 256-col tile
  const int brow = blockIdx.x * 128;

#pragma unroll
  for (int i = 0; i < 4; ++i) wsq_s[t + 256 * i] = wsq[t + 256 * i];

  // A staging (proven conflict-free): lane -> row sub = lane>>3, phys chunk
  // c8p = lane&7; source chunk = c8p ^ sub
  const int sub = lane >> 3;
  const int c8p = lane & 7;
  const size_t asrc = (size_t)(brow + w * 32 + sub) * ND + (size_t)((c8p ^ sub) * 8);

  // B staging, k-paired layout: LDS row r = k>>1 (r = w*32+sub+8q), phys
  // chunk p = lane&7 = (k&1)*4 + (dchunk ^ (r&3)); lane-local inverse:
  //   e = p>>2 (k = 2r+e), dchunk = (p&3) ^ (r&3)  [r&3 == sub&3]
  const size_t bsrc = (size_t)(2 * (w * 32 + sub) + (c8p >> 2)) * ND +
                      (size_t)(((c8p & 3) ^ (sub & 3)) * 8);
  // per q (+8 rows): k advances by 16 -> source += 16*ND; r&3 unchanged.

  // fragment read offsets (u16 units)
  int aofs[2];
#pragma unroll
  for (int kk = 0; kk < 2; ++kk)
    aofs[kk] = (wrb + l15) * 64 + (((kk * 4 + g) ^ (l15 & 7)) * 8);
  // B read: col k = wcb+16n+l15 -> addr = (k>>1)*64 + (k&1)*32 +
  //   ((g ^ ((l15>>1)&3))*8 ; (k>>1)&3 == (l15>>1)&3 (n-independent)
  const int bofs = wcb * 32 + (l15 >> 1) * 64 + (l15 & 1) * 32 +
                   ((g ^ ((l15 >> 1) & 3)) * 8);

  float bestV[4][4], secV[4][4];
  int bestI[4][4];
#pragma unroll
  for (int m = 0; m < 4; ++m)
#pragma unroll
    for (int r = 0; r < 4; ++r) {
      bestV[m][r] = 3.4e38f; secV[m][r] = 3.4e38f; bestI[m][r] = 0;
    }

  f32x4 acc[4][8];
#pragma unroll
  for (int m = 0; m < 4; ++m)
#pragma unroll
    for (int n = 0; n < 8; ++n) acc[m][n] = (f32x4)0.f;

#define ISSUE_A(kc_, ab_)                                                \
  {                                                                      \
    const u16* as_ = Xh + asrc + (kc_) * 64;                             \
    u16* ad_ = Ah + (ab_) * 8192 + w * 32 * 64;                          \
    _Pragma("unroll")                                                    \
    for (int q = 0; q < 4; ++q)                                          \
      gl_lds16(as_ + (size_t)(q * 8) * ND, ad_ + q * 8 * 64);            \
  }
#define ISSUE_B(ct_, sk_, bb_)                                           \
  {                                                                      \
    const u16* bs_ = Wthi + (size_t)(ct_) * 256 * ND + bsrc + (sk_) * 32;\
    u16* bd_ = Bh + (bb_) * 8192 + w * 32 * 64;                          \
    _Pragma("unroll")                                                    \
    for (int q = 0; q < 4; ++q)                                          \
      gl_lds16(bs_ + (size_t)(q * 16) * ND, bd_ + q * 8 * 64);           \
  }
#define DRAIN asm volatile("s_waitcnt vmcnt(0) lgkmcnt(0)" ::: "memory")

  ISSUE_A(0, 0);
  ISSUE_B(0, 0, 0);
  DRAIN;
  __syncthreads();

  for (int s = 0; s < 64; ++s) {
    const int sk = s & 15;          // sub-step within ct (32 d each)
    const int kpar = s & 1;         // which kk half of the A chunk
    const int abuf = (s >> 1) & 1;
    const int bbuf = s & 1;
    if (s < 63) {
      const int s1 = s + 1;
      ISSUE_B(s1 >> 4, s1 & 15, s1 & 1);
      if (s & 1) ISSUE_A(((s1 & 15) >> 1), (s1 >> 1) & 1);
    }
    const u16* Ab = Ah + abuf * 8192;
    const u16* Bb = Bh + bbuf * 8192;
    {
      half8v a_h[4];
#pragma unroll
      for (int m = 0; m < 4; ++m)
        a_h[m] = *(const half8v*)&Ab[aofs[kpar] + m * 1024];
#pragma unroll
      for (int n = 0; n < 8; ++n) {
        half8v b_h = *(const half8v*)&Bb[bofs + n * 512];
#pragma unroll
        for (int m = 0; m < 4; ++m)
          acc[m][n] = mfma16f(a_h[m], b_h, acc[m][n]);
      }
    }
    if (sk == 15) {
      const int ct = s >> 4;
      // epilogue for ct. C layout: col = 16n + l15, row = 16m + 4g + r
#pragma unroll
      for (int n = 0; n < 8; ++n) {
        int col = ct * 256 + wcb + 16 * n + l15;
        float wq = wsq_s[col];
#pragma unroll
        for (int m = 0; m < 4; ++m)
#pragma unroll
          for (int r = 0; r < 4; ++r) {
            float v = wq - 2.0f * acc[m][n][r];
            if (v < bestV[m][r]) {
              secV[m][r] = bestV[m][r];
              bestV[m][r] = v;
              bestI[m][r] = col;
            } else if (v < secV[m][r]) {
              secV[m][r] = v;
            }
          }
      }
#pragma unroll
      for (int m = 0; m < 4; ++m)
#pragma unroll
        for (int n = 0; n < 8; ++n) acc[m][n] = (f32x4)0.f;
    }
    DRAIN;             // next-step tiles landed (issued before compute)
    __syncthreads();
  }
#undef ISSUE_A
#undef ISSUE_B
#undef DRAIN

  // cross-lane reduce: 16 lanes share each row; merge (b1,idx,b2)
#pragma unroll
  for (int m = 0; m < 4; ++m)
#pragma unroll
    for (int r = 0; r < 4; ++r) {
      float v = bestV[m][r];
      float sec = secV[m][r];
      int idx = bestI[m][r];
#pragma unroll
      for (int mask = 1; mask < 16; mask <<= 1) {
        float ov = __shfl_xor(v, mask, 64);
        float os = __shfl_xor(sec, mask, 64);
        int oi = __shfl_xor(idx, mask, 64);
        float nsec = fminf(fminf(sec, os), fmaxf(v, ov));
        if (ov < v || (ov == v && oi < idx)) { v = ov; idx = oi; }
        sec = nsec;
      }
      if (l15 == 0) {
        int rowl = wrb + 16 * m + 4 * g + r;
        redV[rowl][w & 1] = v;
        redS[rowl][w & 1] = sec;
        redI[rowl][w & 1] = idx;
      }
    }
  __syncthreads();
  if (t < 128) {
    float v0 = redV[t][0], v1 = redV[t][1];
    float s0 = redS[t][0], s1 = redS[t][1];
    int i0 = redI[t][0], i1 = redI[t][1];
    float bv, sec;
    int bi;
    if (v1 < v0 || (v1 == v0 && i1 < i0)) { bv = v1; bi = i1; }
    else { bv = v0; bi = i0; }
    sec = fminf(fminf(s0, s1), fmaxf(v0, v1));
    int b = brow + t;
    argmin_i[b] = bi;
    argmin_f[b] = (float)bi;
    atomicAdd(&counts[bi], 1);
    atomicAdd(&bhist[(size_t)bi * NC + cls[b]], 1.0f);
    if (sec - bv < TAU) {
      int slot = atomicAdd(flagCnt, 1);
      if (slot < FLAG_CAP) flagList[slot] = b;
    }
  }
}

// ----- kernel 3: exact f32 rescore + in-place apply (block owns its rows) ---
__global__ __launch_bounds__(256) void fixup_kernel(
    const float* __restrict__ X, const float* __restrict__ Wt32,
    const float* __restrict__ wsq, const int* __restrict__ flagCnt,
    const int* __restrict__ flagList, const int* __restrict__ cls,
    int* __restrict__ argmin_i, float* __restrict__ argmin_f,
    int* __restrict__ counts, float* __restrict__ bhist) {
  __shared__ float xs[FROWS][ND];
  __shared__ int rows[FROWS];
  __shared__ u64 wred[4][FROWS];
  int n = *flagCnt;
  if (n > FLAG_CAP) n = FLAG_CAP;
  int r0 = blockIdx.x * FROWS;
  if (r0 >= n) return;
  int nr = n - r0; if (nr > FROWS) nr = FROWS;
  int t = threadIdx.x;
  if (t < FROWS) rows[t] = flagList[r0 + (t < nr ? t : 0)];
  __syncthreads();
  for (int j = t; j < FROWS * (ND / 4); j += 256) {
    int r = j >> 7, c = j & 127;
    ((float4*)xs[r])[c] = ((const float4*)(X + (size_t)rows[r] * ND))[c];
  }
  __syncthreads();

  const int k0 = t * 4;
  const float4* w0 = (const float4*)(Wt32 + (size_t)(k0 + 0) * ND);
  const float4* w1 = (const float4*)(Wt32 + (size_t)(k0 + 1) * ND);
  const float4* w2 = (const float4*)(Wt32 + (size_t)(k0 + 2) * ND);
  const float4* w3 = (const float4*)(Wt32 + (size_t)(k0 + 3) * ND);
  float a[4][FROWS];
#pragma unroll
  for (int kk = 0; kk < 4; ++kk)
#pragma unroll
    for (int r = 0; r < FROWS; ++r) a[kk][r] = 0.f;

  for (int d = 0; d < ND / 4; ++d) {
    float4 v0 = w0[d], v1 = w1[d], v2 = w2[d], v3 = w3[d];
#pragma unroll
    for (int r = 0; r < FROWS; ++r) {
      float4 x4 = ((const float4*)xs[r])[d];
      a[0][r] += x4.x * v0.x + x4.y * v0.y + x4.z * v0.z + x4.w * v0.w;
      a[1][r] += x4.x * v1.x + x4.y * v1.y + x4.z * v1.z + x4.w * v1.w;
      a[2][r] += x4.x * v2.x + x4.y * v2.y + x4.z * v2.z + x4.w * v2.w;
      a[3][r] += x4.x * v3.x + x4.y * v3.y + x4.z * v3.z + x4.w * v3.w;
    }
  }

  float wq0 = wsq[k0], wq1 = wsq[k0 + 1], wq2 = wsq[k0 + 2], wq3 = wsq[k0 + 3];
  const int wv_ = t >> 6, lane = t & 63;
#pragma unroll
  for (int r = 0; r < FROWS; ++r) {
    float bv = wq0 - 2.0f * a[0][r];
    int bk = k0;
    float v;
    v = wq1 - 2.0f * a[1][r]; if (v < bv) { bv = v; bk = k0 + 1; }
    v = wq2 - 2.0f * a[2][r]; if (v < bv) { bv = v; bk = k0 + 2; }
    v = wq3 - 2.0f * a[3][r]; if (v < bv) { bv = v; bk = k0 + 3; }
    u64 key = ((u64)f32_sortable(bv) << 32) | (u32)bk;
#pragma unroll
    for (int m = 1; m < 64; m <<= 1) {
      u64 o = __shfl_xor(key, m, 64);
      if (o < key) key = o;
    }
    if (lane == 0) wred[wv_][r] = key;
  }
  __syncthreads();
  if (t < nr) {
    u64 k = wred[0][t];
    if (wred[1][t] < k) k = wred[1][t];
    if (wred[2][t] < k) k = wred[2][t];
    if (wred[3][t] < k) k = wred[3][t];
    int nk = (int)(u32)(k & 0xffffffffu);
    int row = rows[t];
    int old = argmin_i[row];
    if (nk != old) {
      argmin_i[row] = nk;
      argmin_f[row] = (float)nk;
      atomicSub(&counts[old], 1);
      atomicAdd(&counts[nk], 1);
      int c = cls[row];
      atomicAdd(&bhist[(size_t)old * NC + c], -1.0f);
      atomicAdd(&bhist[(size_t)nk * NC + c], 1.0f);
    }
  }
}

// -------- kernel 4: scan + cluster_size EMA + cs_norm -------
__global__ __launch_bounds__(1024) void scan_kernel(
    const int* __restrict__ counts, const float* __restrict__ cluster_size,
    float* __restrict__ out_ncs, float* __restrict__ csnorm,
    int* __restrict__ offsets) {
  __shared__ float wsum[16];
  __shared__ int wcnt[16];
  int t = threadIdx.x, lane = t & 63, wv = t >> 6;
  int cnt = counts[t];
  float ncs = cluster_size[t] * 0.99f + 0.01f * (cnt == 0 ? 1.0f : (float)cnt);
  out_ncs[t] = ncs;

  float s = ncs;
#pragma unroll
  for (int m = 1; m < 64; m <<= 1) s += __shfl_xor(s, m, 64);
  int ic = cnt;
#pragma unroll
  for (int o = 1; o < 64; o <<= 1) {
    int v = __shfl_up(ic, o, 64);
    if (lane >= o) ic += v;
  }
  if (lane == 63) { wsum[wv] = s; wcnt[wv] = ic; }
  __syncthreads();
  float n = 0.f;
  int coff = 0;
  for (int i = 0; i < 16; ++i) {
    n += wsum[i];
    if (i < wv) coff += wcnt[i];
  }
  csnorm[t] = (ncs + 1e-5f) / (n + 1024.0f * 1e-5f) * n;
  offsets[t] = coff + ic - cnt;
}

// --------- kernel 5: reorder rows (writes korder) + zero esum ---------------
__global__ __launch_bounds__(256) void reorder_kernel(
    const int* __restrict__ argmin_i, const int* __restrict__ offsets,
    int* __restrict__ cursor, int* __restrict__ order,
    int* __restrict__ korder, float* __restrict__ esum) {
  int b = blockIdx.x * 256 + threadIdx.x;
  // zero esum (524288 floats across 65536 threads, 8 each)
  float4 z = make_float4(0.f, 0.f, 0.f, 0.f);
  *(float4*)(esum + (size_t)b * 8) = z;
  *(float4*)(esum + (size_t)b * 8 + 4) = z;
  int k = argmin_i[b];
  int pos = atomicAdd(&cursor[k], 1);
  int o = offsets[k] + pos;
  order[o] = b;
  korder[o] = k;
}

// -------- kernel 6: balanced chunk-scan gather with run-boundary atomics ----
__global__ __launch_bounds__(256) void gather_runs(
    const float* __restrict__ X, const int* __restrict__ order,
    const int* __restrict__ korder, float* __restrict__ esum) {
  __shared__ int so[GROWS];
  __shared__ int sk[GROWS];
  int t = threadIdx.x;
  int base = blockIdx.x * GROWS;
  if (t < GROWS) {
    so[t] = order[base + t];
    sk[t] = korder[base + t];
  }
  __syncthreads();
  float a0 = 0.f, a1 = 0.f;
  int curk = sk[0];
#pragma unroll 8
  for (int m = 0; m < GROWS; ++m) {
    int k = sk[m];
    if (k != curk) {   // uniform across block
      atomicAdd(&esum[(size_t)curk * ND + 2 * t], a0);
      atomicAdd(&esum[(size_t)curk * ND + 2 * t + 1], a1);
      a0 = 0.f; a1 = 0.f; curk = k;
    }
    float2 v = *(const float2*)(X + (size_t)so[m] * ND + 2 * t);
    a0 += v.x;
    a1 += v.y;
  }
  atomicAdd(&esum[(size_t)curk * ND + 2 * t], a0);
  atomicAdd(&esum[(size_t)curk * ND + 2 * t + 1], a1);
}

// --- kernel 7: fused: blocks [0,512) embed_avg EMA + weight (transpose);
//               blocks [512,912) hist EMA ---
__global__ __launch_bounds__(256) void ema_hist_kernel(
    const float* __restrict__ esum, const float* __restrict__ embed_avg,
    const float* __restrict__ csnorm, const float* __restrict__ hist,
    const float* __restrict__ bhist, float* __restrict__ out_w,
    float* __restrict__ out_ea, float* __restrict__ out_hist) {
  __shared__ float tile[32][33];
  int t = threadIdx.x;
  if (blockIdx.x >= 512) {
    int i = (blockIdx.x - 512) * 256 + t;
    out_hist[i] = hist[i] * 0.99f + 0.01f * bhist[i];
    return;
  }
  int kb = blockIdx.x & 31;
  int db = blockIdx.x >> 5;
  int tx = t & 31, ty = t >> 5;
#pragma unroll
  for (int i = 0; i < 4; ++i) {
    int kl = ty + i * 8;
    tile[kl][tx] = esum[(size_t)(kb * 32 + kl) * ND + db * 32 + tx];
  }
  __syncthreads();
#pragma unroll
  for (int i = 0; i < 4; ++i) {
    int d = db * 32 + ty + i * 8;
    int k = kb * 32 + tx;
    size_t idx = (size_t)d * NK + k;
    float nea = embed_avg[idx] * 0.99f + 0.01f * tile[tx][ty + i * 8];
    out_ea[idx] = nea;
    out_w[idx] = nea / csnorm[k];
  }
}

extern "C" void kernel_launch(void* const* d_in, const int* in_sizes, int n_in,
                              void* d_out, int out_size, void* d_ws, size_t ws_size,
                              hipStream_t stream) {
  const float* X = (const float*)d_in[0];
  const int* cls = (const int*)d_in[1];
  const float* W = (const float*)d_in[2];
  const float* cluster_size = (const float*)d_in[3];
  const float* embed_avg = (const float*)d_in[4];
  const float* hist = (const float*)d_in[5];

  float* wsf = (float*)d_ws;
  int* wsi = (int*)d_ws;
  int* counts = wsi + OFF_COUNTS;
  int* cursor = wsi + OFF_CURSOR;
  float* bhist = wsf + OFF_BHIST;
  int* flagCnt = wsi + OFF_FLAGCNT;
  float* wsq = wsf + OFF_WSQ;
  int* flagList = wsi + OFF_FLAGLIST;
  float* csnorm = wsf + OFF_CSNORM;
  int* offsets = wsi + OFF_OFFSETS;
  int* argmin_i = wsi + OFF_ARGMIN;
  int* order = wsi + OFF_ORDER;
  int* korder = wsi + OFF_KORDER;
  u16* Wthi = (u16*)(wsf + OFF_WTHI);
  float* Wt32 = wsf + OFF_WT32;
  u16* Xh = (u16*)(wsf + OFF_XH);
  float* esum = wsf + OFF_ESUM;

  float* out = (float*)d_out;
  float* out_w = out;
  float* out_ncs = out + (size_t)ND * NK;
  float* out_ea = out_ncs + NK;
  float* out_hist = out_ea + (size_t)ND * NK;
  float* out_arg = out_hist + (size_t)NK * NC;

  hipMemsetAsync(d_ws, 0, (size_t)OFF_ZERO_END * 4, stream);

  prep_all<<<512 + NB * ND / 8 / 256, 256, 0, stream>>>(W, X, Wthi, Wt32, Xh,
                                                        wsq);
  argmin_pair<<<NB / 128, 256, 0, stream>>>(Xh, Wthi, wsq, cls, argmin_i,
                                            out_arg, counts, bhist, flagCnt,
                                            flagList);
  fixup_kernel<<<FLAG_CAP / FROWS, 256, 0, stream>>>(X, Wt32, wsq, flagCnt,
                                                     flagList, cls, argmin_i,
                                                     out_arg, counts, bhist);
  scan_kernel<<<1, 1024, 0, stream>>>(counts, cluster_size, out_ncs, csnorm,
                                      offsets);
  reorder_kernel<<<NB / 256, 256, 0, stream>>>(argmin_i, offsets, cursor, order,
                                               korder, esum);
  gather_runs<<<NB / GROWS, 256, 0, stream>>>(X, order, korder, esum);
  ema_hist_kernel<<<512 + (NK * NC) / 256, 256, 0, stream>>>(
      esum, embed_avg, csnorm, hist, bhist, out_w, out_ea, out_hist);
}